// Round 20
// baseline (404.735 us; speedup 1.0000x reference)
//
#include <hip/hip_runtime.h>

// ---------------------------------------------------------------------------
// FullModelSnowflake.  R19: row-local chain fusion — knn+gcn0 in one kernel;
// gcnGEMM+encGEMM+QKV0 in one kernel; FFN2+LN+nextQKV in one kernel.
// 28 -> 22 launches.
// ---------------------------------------------------------------------------

#define B_ 2
#define N_ 1024
#define D_ 128
#define H_ 8
#define DK_ 16
#define L_ 4
#define KG_ 16
#define KLOC_ 8
#define COARSE_ 512
#define AW_ 8            // waves per attention block
#define KSP_ 4           // block-level key splits
#define PREC_ 17         // floats per attention partial (sum + 16 acc)
#define QPL_ 4           // queries per lane

static __device__ __forceinline__ float half_sum(float v) {
    #pragma unroll
    for (int off = 16; off > 0; off >>= 1) v += __shfl_xor(v, off);
    return v;
}

// GEMM step: acc += Xs[8][CIN] @ W[:, col0:col0+128]; W staged via Ws (64x128).
static __device__ __forceinline__ float4 lds_gemm(
        const float* Xs, float* Ws, const float* __restrict__ W,
        int wstride, int col0, float4 acc, int CIN,
        int tid, int rowl, int col4) {
    for (int c0 = 0; c0 < CIN; c0 += 64) {
        __syncthreads();
        #pragma unroll
        for (int i = 0; i < 8; ++i) {
            int flat = tid + i * 256;
            int wr = flat >> 5, wc = (flat & 31) << 2;
            *(float4*)&Ws[wr * 128 + wc] =
                *(const float4*)(W + (size_t)(c0 + wr) * wstride + col0 + wc);
        }
        __syncthreads();
        const float* xrow = Xs + rowl * CIN + c0;
        #pragma unroll 4
        for (int c = 0; c < 64; ++c) {
            float xv = xrow[c];
            float4 w = *(const float4*)&Ws[c * 128 + col4];
            acc.x += xv * w.x; acc.y += xv * w.y;
            acc.z += xv * w.z; acc.w += xv * w.w;
        }
    }
    return acc;
}

// head-major QKV write helper
static __device__ __forceinline__ void qkv_write(
        float* __restrict__ Y, int row, int col4, float4 acc) {
    int b = row >> 10, n = row & (N_ - 1);
    int h = col4 >> 4, d = col4 & 15;
    *(float4*)(Y + (((size_t)(b * 8 + h) * N_ + n) << 4) + d) = acc;
}

// ---------------- KNN (k=16) + GCN layer-1 fused ---------------------------
// One wave per query: scan all 1024 candidates (16/lane), 16 rounds of
// butterfly min-extraction accumulating neighbor coords; then each lane
// computes one column of the 3->64 linear (+relu).
__global__ __launch_bounds__(256) void knn_gcn0_kernel(
        const float* __restrict__ coords,
        const float* __restrict__ w0, const float* __restrict__ b0,
        int* __restrict__ knn, float* __restrict__ x64) {
    __shared__ float4 sc[N_];
    int wid = threadIdx.x >> 6;
    int lane = threadIdx.x & 63;
    size_t q = (size_t)blockIdx.x * 4 + wid;
    int b = (int)(q >> 10), n = (int)(q & (N_ - 1));
    const float* cb = coords + (size_t)b * N_ * 3;
    for (int i = threadIdx.x; i < N_; i += 256) {
        float x = cb[i * 3], y = cb[i * 3 + 1], z = cb[i * 3 + 2];
        sc[i] = make_float4(x, y, z, x * x + y * y + z * z);
    }
    __syncthreads();
    float4 qc = sc[n];
    float qx = qc.x, qy = qc.y, qz = qc.z, q2 = qc.w;
    float ld[16];
    #pragma unroll
    for (int j = 0; j < 16; ++j) {
        int m = (j << 6) | lane;
        float4 c = sc[m];
        float dot = qx * c.x + qy * c.y + qz * c.z;
        float d = (q2 - 2.0f * dot) + c.w;
        ld[j] = (m == n) ? 3e38f : d;
    }
    int* o = knn + q * KG_;
    float ax = qx, ay = qy, az = qz;     // self + neighbors
    #pragma unroll
    for (int r = 0; r < KG_; ++r) {
        float dm = ld[0]; int im = lane;
        #pragma unroll
        for (int j = 1; j < 16; ++j) {
            int mj = (j << 6) | lane;
            bool lt = (ld[j] < dm) || (ld[j] == dm && mj < im);
            dm = lt ? ld[j] : dm; im = lt ? mj : im;
        }
        #pragma unroll
        for (int off = 32; off > 0; off >>= 1) {
            float d2 = __shfl_xor(dm, off); int i2 = __shfl_xor(im, off);
            bool lt = (d2 < dm) || (d2 == dm && i2 < im);
            dm = lt ? d2 : dm; im = lt ? i2 : im;
        }
        if (lane == 0) o[r] = im;
        float4 w = sc[im];               // broadcast
        ax += w.x; ay += w.y; az += w.z;
        if ((im & 63) == lane) {
            #pragma unroll
            for (int j = 0; j < 16; ++j) if ((im >> 6) == j) ld[j] = 3e38f;
        }
    }
    float s = 1.0f / (KG_ + 1);
    ax *= s; ay *= s; az *= s;
    float acc = b0[lane] + ax * w0[lane] + ay * w0[64 + lane] + az * w0[128 + lane];
    x64[q * 64 + lane] = fmaxf(acc, 0.f);
}

// ---------------- encoder fused: gcnGEMM + encGEMM + layer-0 QKV -----------
__global__ __launch_bounds__(256) void enc_fused_kernel(
        const float* __restrict__ x64, const int* __restrict__ knn,
        const float* __restrict__ w1, const float* __restrict__ b1,
        const float* __restrict__ enc_fw, const float* __restrict__ enc_fb,
        const float* __restrict__ Wq, const float* __restrict__ bq,
        const float* __restrict__ Wk, const float* __restrict__ bk,
        const float* __restrict__ Wv, const float* __restrict__ bv,
        float* __restrict__ x, float* __restrict__ Q,
        float* __restrict__ K, float* __restrict__ V) {
    __shared__ float Xs64[8 * 64];
    __shared__ float Ws[64 * 128];
    __shared__ float Xa[8 * 128];
    __shared__ float Xe[8 * 128];
    int tid = threadIdx.x;
    int row0 = blockIdx.x * 8;
    int col4 = (tid & 31) << 2;
    int rowl = tid >> 5;
    // gather-stage: agg of x64 (knn mean)
    #pragma unroll
    for (int i = 0; i < 2; ++i) {
        int idx = tid + i * 256;
        int r = idx >> 6, c = idx & 63;
        int row = row0 + r;
        int b = row >> 10;
        const int* id = knn + (size_t)row * KG_;
        float val = x64[(size_t)row * 64 + c];
        #pragma unroll
        for (int j = 0; j < KG_; ++j)
            val += x64[((size_t)(b << 10) + id[j]) * 64 + c];
        Xs64[idx] = val * (1.0f / (KG_ + 1));
    }
    // gcn layer-2 GEMM 64->128 + relu
    float4 a1 = *(const float4*)(b1 + col4);
    a1 = lds_gemm(Xs64, Ws, w1, 128, 0, a1, 64, tid, rowl, col4);
    a1.x = fmaxf(a1.x, 0.f); a1.y = fmaxf(a1.y, 0.f);
    a1.z = fmaxf(a1.z, 0.f); a1.w = fmaxf(a1.w, 0.f);
    __syncthreads();
    *(float4*)&Xa[rowl * 128 + col4] = a1;
    // enc GEMM 128->128
    float4 a2 = *(const float4*)(enc_fb + col4);
    a2 = lds_gemm(Xa, Ws, enc_fw, 128, 0, a2, 128, tid, rowl, col4);
    int row = row0 + rowl;
    *(float4*)(x + (size_t)row * D_ + col4) = a2;
    __syncthreads();
    *(float4*)&Xe[rowl * 128 + col4] = a2;
    // layer-0 QKV
    float4 aq = *(const float4*)(bq + col4);
    aq = lds_gemm(Xe, Ws, Wq, 128, 0, aq, 128, tid, rowl, col4);
    qkv_write(Q, row, col4, aq);
    float4 ak = *(const float4*)(bk + col4);
    ak = lds_gemm(Xe, Ws, Wk, 128, 0, ak, 128, tid, rowl, col4);
    qkv_write(K, row, col4, ak);
    float4 av = *(const float4*)(bv + col4);
    av = lds_gemm(Xe, Ws, Wv, 128, 0, av, 128, tid, rowl, col4);
    qkv_write(V, row, col4, av);
}

// ---------------- FFN2 GEMM + residual + LN + next-layer QKV ---------------
template <bool LAST>
__global__ __launch_bounds__(256) void lnqkv_kernel(
        const float* __restrict__ ffh,
        const float* __restrict__ W2, const float* __restrict__ b2,
        const float* __restrict__ res,
        const float* __restrict__ g, const float* __restrict__ bt,
        const float* __restrict__ Wq, const float* __restrict__ bq,
        const float* __restrict__ Wk, const float* __restrict__ bk,
        const float* __restrict__ Wv, const float* __restrict__ bv,
        float* __restrict__ x, float* __restrict__ Q,
        float* __restrict__ K, float* __restrict__ V) {
    __shared__ float Xs[8 * 512];
    __shared__ float Ws[64 * 128];
    __shared__ float Xe[8 * 128];
    int tid = threadIdx.x;
    int row0 = blockIdx.x * 8;
    int col4 = (tid & 31) << 2;
    int rowl = tid >> 5;
    {
        const float4* xg = (const float4*)(ffh + (size_t)row0 * 512);
        float4* xs4 = (float4*)Xs;
        #pragma unroll
        for (int i = 0; i < 4; ++i) xs4[tid + i * 256] = xg[tid + i * 256];
    }
    float4 acc = *(const float4*)(b2 + col4);
    acc = lds_gemm(Xs, Ws, W2, 128, 0, acc, 512, tid, rowl, col4);
    int row = row0 + rowl;
    float4 r = *(const float4*)(res + (size_t)row * D_ + col4);
    acc.x += r.x; acc.y += r.y; acc.z += r.z; acc.w += r.w;
    float mean = half_sum(acc.x + acc.y + acc.z + acc.w) * (1.0f / D_);
    float dx = acc.x - mean, dy = acc.y - mean, dz = acc.z - mean, dw = acc.w - mean;
    float var = half_sum(dx * dx + dy * dy + dz * dz + dw * dw) * (1.0f / D_);
    float rstd = rsqrtf(var + 1e-5f);
    float4 gv = *(const float4*)(g + col4);
    float4 bv4 = *(const float4*)(bt + col4);
    float4 o;
    o.x = dx * rstd * gv.x + bv4.x;
    o.y = dy * rstd * gv.y + bv4.y;
    o.z = dz * rstd * gv.z + bv4.z;
    o.w = dw * rstd * gv.w + bv4.w;
    *(float4*)(x + (size_t)row * D_ + col4) = o;
    if (!LAST) {
        __syncthreads();
        *(float4*)&Xe[rowl * 128 + col4] = o;
        float4 aq = *(const float4*)(bq + col4);
        aq = lds_gemm(Xe, Ws, Wq, 128, 0, aq, 128, tid, rowl, col4);
        qkv_write(Q, row, col4, aq);
        float4 ak = *(const float4*)(bk + col4);
        ak = lds_gemm(Xe, Ws, Wk, 128, 0, ak, 128, tid, rowl, col4);
        qkv_write(K, row, col4, ak);
        float4 av = *(const float4*)(bv + col4);
        av = lds_gemm(Xe, Ws, Wv, 128, 0, av, 128, tid, rowl, col4);
        qkv_write(V, row, col4, av);
    }
}

// FFN1 GEMM with fused attn-final-merge + residual + LN in the X-stage.
__global__ __launch_bounds__(256) void gemm_ffn1_kernel(
        const float* __restrict__ pp, const float* __restrict__ xin,
        const float* __restrict__ g, const float* __restrict__ bt,
        const float* __restrict__ W, const float* __restrict__ bias,
        float* __restrict__ xln, float* __restrict__ Y) {
    __shared__ float Xs[8 * 128];
    __shared__ float Ws[64 * 128];
    int tid = threadIdx.x;
    int row0 = blockIdx.x * 8;
    int col0 = blockIdx.y * 128;
    int col4 = (tid & 31) << 2;
    int rowl = tid >> 5;
    {
        int row = row0 + rowl;
        int b = row >> 10, n = row & (N_ - 1);
        int h = col4 >> 4, d0 = col4 & 15;
        const float* p = pp + (((size_t)(b * 8 + h) * N_ + n) * KSP_) * PREC_;
        float gsum = 0.f, a0 = 0.f, a1 = 0.f, a2 = 0.f, a3 = 0.f;
        #pragma unroll
        for (int s = 0; s < KSP_; ++s) {
            const float* ps = p + s * PREC_;
            gsum += ps[0];
            a0 += ps[1 + d0]; a1 += ps[2 + d0]; a2 += ps[3 + d0]; a3 += ps[4 + d0];
        }
        float inv = 1.0f / gsum;
        float4 xv = *(const float4*)(xin + (size_t)row * D_ + col4);
        float v0 = a0 * inv + xv.x;
        float v1 = a1 * inv + xv.y;
        float v2 = a2 * inv + xv.z;
        float v3 = a3 * inv + xv.w;
        float mean = half_sum(v0 + v1 + v2 + v3) * (1.0f / D_);
        float dx = v0 - mean, dy = v1 - mean, dz = v2 - mean, dw = v3 - mean;
        float var = half_sum(dx * dx + dy * dy + dz * dz + dw * dw) * (1.0f / D_);
        float rstd = rsqrtf(var + 1e-5f);
        float4 gv = *(const float4*)(g + col4);
        float4 bv = *(const float4*)(bt + col4);
        float4 o;
        o.x = dx * rstd * gv.x + bv.x;
        o.y = dy * rstd * gv.y + bv.y;
        o.z = dz * rstd * gv.z + bv.z;
        o.w = dw * rstd * gv.w + bv.w;
        *(float4*)&Xs[rowl * 128 + col4] = o;
        if (blockIdx.y == 0)
            *(float4*)(xln + (size_t)row * D_ + col4) = o;
    }
    float4 acc = *(const float4*)(bias + col0 + col4);
    acc = lds_gemm(Xs, Ws, W, 512, col0, acc, 128, tid, rowl, col4);
    acc.x = fmaxf(acc.x, 0.f); acc.y = fmaxf(acc.y, 0.f);
    acc.z = fmaxf(acc.z, 0.f); acc.w = fmaxf(acc.w, 0.f);
    int row = row0 + rowl;
    *(float4*)(Y + (size_t)row * 512 + col0 + col4) = acc;
}

// ---------------- single-kernel local-KNN + mean + seed linear -------------
__global__ __launch_bounds__(256) void loc_fused_kernel(
        const float* __restrict__ part, const float* __restrict__ pred,
        const float* __restrict__ sw1, const float* __restrict__ sb1,
        float* __restrict__ seedh, int Nq) {
    __shared__ float4 sc[N_];
    int wid = threadIdx.x >> 6;
    int lane = threadIdx.x & 63;
    size_t q = (size_t)blockIdx.x * 4 + wid;
    int b = (int)(q / Nq);
    const float* pb = part + (size_t)b * N_ * 3;
    for (int i = threadIdx.x; i < N_; i += 256) {
        float x = pb[i * 3], y = pb[i * 3 + 1], z = pb[i * 3 + 2];
        sc[i] = make_float4(x, y, z, x * x + y * y + z * z);
    }
    __syncthreads();
    const float* pr = pred + q * 3;
    float qx = pr[0], qy = pr[1], qz = pr[2];
    float q2 = qx * qx + qy * qy + qz * qz;
    float ld[16];
    #pragma unroll
    for (int j = 0; j < 16; ++j) {
        int m = (j << 6) | lane;
        float4 c = sc[m];
        float dot = qx * c.x + qy * c.y + qz * c.z;
        ld[j] = (q2 - 2.0f * dot) + c.w;
    }
    float sx = 0.f, sy = 0.f, sz = 0.f;
    #pragma unroll
    for (int r = 0; r < KLOC_; ++r) {
        float dm = ld[0]; int im = lane;
        #pragma unroll
        for (int j = 1; j < 16; ++j) {
            int mj = (j << 6) | lane;
            bool lt = (ld[j] < dm) || (ld[j] == dm && mj < im);
            dm = lt ? ld[j] : dm; im = lt ? mj : im;
        }
        #pragma unroll
        for (int off = 32; off > 0; off >>= 1) {
            float d2 = __shfl_xor(dm, off); int i2 = __shfl_xor(im, off);
            bool lt = (d2 < dm) || (d2 == dm && i2 < im);
            dm = lt ? d2 : dm; im = lt ? i2 : im;
        }
        float4 w = sc[im];               // broadcast
        sx += w.x; sy += w.y; sz += w.z;
        if ((im & 63) == lane) {
            #pragma unroll
            for (int j = 0; j < 16; ++j) if ((im >> 6) == j) ld[j] = 3e38f;
        }
    }
    float comb[6];
    comb[0] = qx; comb[1] = qy; comb[2] = qz;
    comb[3] = sx * (1.0f / KLOC_);
    comb[4] = sy * (1.0f / KLOC_);
    comb[5] = sz * (1.0f / KLOC_);
    float* so = seedh + q * 128;
    #pragma unroll
    for (int half = 0; half < 2; ++half) {
        int c = lane + half * 64;
        float acc = sb1[c];
        #pragma unroll
        for (int i = 0; i < 6; ++i) acc += comb[i] * sw1[i * 128 + c];
        so[c] = fmaxf(acc, 0.f);
    }
}

// ---------------- refine tail: seed GEMM + convt + child in one kernel -----
__global__ __launch_bounds__(256) void refine_tail_kernel(
        const float* __restrict__ seedh,
        const float* __restrict__ sw2, const float* __restrict__ sb2,
        const float* __restrict__ dw, const float* __restrict__ db,
        const float* __restrict__ cw, const float* __restrict__ cb,
        const float* __restrict__ pred, float* __restrict__ outp) {
    __shared__ float Xs[8 * 128];
    __shared__ float Ws[64 * 128];
    __shared__ float Sd[8 * 128];
    __shared__ float Hb[8 * 256];
    int tid = threadIdx.x;
    int row0 = blockIdx.x * 8;
    int col4 = (tid & 31) << 2;
    int rowl = tid >> 5;
    {
        const float4* xg = (const float4*)(seedh + (size_t)row0 * 128);
        float4* xs4 = (float4*)Xs;
        xs4[tid] = xg[tid];
    }
    float4 acc = *(const float4*)(sb2 + col4);
    acc = lds_gemm(Xs, Ws, sw2, 128, 0, acc, 128, tid, rowl, col4);
    __syncthreads();
    *(float4*)&Sd[rowl * 128 + col4] = acc;
    #pragma unroll
    for (int panel = 0; panel < 2; ++panel) {
        int col0 = panel * 128;
        float4 a2;
        a2.x = db[(col0 + col4) >> 1];
        a2.y = db[(col0 + col4 + 1) >> 1];
        a2.z = db[(col0 + col4 + 2) >> 1];
        a2.w = db[(col0 + col4 + 3) >> 1];
        a2 = lds_gemm(Sd, Ws, dw, 256, col0, a2, 128, tid, rowl, col4);
        a2.x = fmaxf(a2.x, 0.f); a2.y = fmaxf(a2.y, 0.f);
        a2.z = fmaxf(a2.z, 0.f); a2.w = fmaxf(a2.w, 0.f);
        __syncthreads();
        *(float4*)&Hb[rowl * 256 + col0 + col4] = a2;
    }
    __syncthreads();
    if (tid < 48) {
        int r = tid / 6, rem = tid % 6;
        int t = rem / 3, p = rem % 3;
        const float* hr = Hb + r * 256;
        float a = cb[p];
        #pragma unroll 4
        for (int o = 0; o < 128; ++o) a += hr[o * 2 + t] * cw[p * 128 + o];
        size_t row = row0 + r;
        outp[row * 6 + t * 3 + p] = pred[row * 3 + p] + a;
    }
}

// ---------------- decoder: dec_w1 + dec_w2 fused ---------------------------
__global__ __launch_bounds__(256) void dec12_kernel(
        const float* __restrict__ gc,
        const float* __restrict__ w1, const float* __restrict__ b1,
        const float* __restrict__ w2, const float* __restrict__ b2,
        float* __restrict__ pts0) {
    __shared__ float gcs[128];
    __shared__ float dech[128];
    int tid = threadIdx.x;
    int row = blockIdx.x / 6;
    int colb = (blockIdx.x % 6) * 256;
    if (tid < 128) gcs[tid] = gc[row * 128 + tid];
    __syncthreads();
    if (tid < 128) {
        float a = b1[tid];
        #pragma unroll 4
        for (int c = 0; c < 128; ++c) a += gcs[c] * w1[c * 128 + tid];
        dech[tid] = fmaxf(a, 0.f);
    }
    __syncthreads();
    int col = colb + tid;
    float a = b2[col];
    #pragma unroll 4
    for (int c = 0; c < 128; ++c) a += dech[c] * w2[(size_t)c * 1536 + col];
    pts0[(size_t)row * 1536 + col] = a;
}

// ---------------- attention: 4 queries/lane, LDS-staged K/V ----------------
__global__ __launch_bounds__(512) void attn_part(
        const float* __restrict__ q,
        const float* __restrict__ k,
        const float* __restrict__ v,
        const float* __restrict__ coords,
        const float* __restrict__ alphap, int layer,
        float* __restrict__ pp) {
    __shared__ float smem[10304];    // stage 8192 | merge: ssum 2048 + sacc 8256
    float* kst = smem;               // [256][16]
    float* vst = smem + 4096;        // [256][16]
    float* ssum = smem;              // [8][256]   (merge phase)
    float* sacc = smem + 2048;       // [64][129]
    int bh = blockIdx.x & 15;        // b*8 + h
    int t = blockIdx.x >> 4;         // nb*KSP + ks
    int ks = t & (KSP_ - 1);
    int nb = t >> 2;                 // [0, 4)
    int b = bh >> 3;
    int wid = threadIdx.x >> 6;
    int lane = threadIdx.x & 63;
    float alpha = alphap[layer];
    {
        const float4* kg = (const float4*)(k + (((size_t)bh * N_ + ks * 256) << 4));
        const float4* vg = (const float4*)(v + (((size_t)bh * N_ + ks * 256) << 4));
        float4* ks4 = (float4*)kst;
        float4* vs4 = (float4*)vst;
        #pragma unroll
        for (int i = 0; i < 2; ++i) {
            int idx = threadIdx.x + i * 512;
            ks4[idx] = kg[idx];
            vs4[idx] = vg[idx];
        }
    }
    int n0 = nb * 256 + lane;        // queries n0 + u*64, u=0..3
    const float* cb = coords + (size_t)b * N_ * 3;
    float qv[QPL_][DK_];
    float cx[QPL_], cy[QPL_], cz[QPL_];
    #pragma unroll
    for (int u = 0; u < QPL_; ++u) {
        const float* qp = q + (((size_t)bh * N_ + n0 + u * 64) << 4);
        #pragma unroll
        for (int d = 0; d < DK_; ++d) qv[u][d] = qp[d];
        int nn = n0 + u * 64;
        cx[u] = cb[nn * 3]; cy[u] = cb[nn * 3 + 1]; cz[u] = cb[nn * 3 + 2];
    }
    float sm[QPL_];
    float acc[QPL_][DK_];
    #pragma unroll
    for (int u = 0; u < QPL_; ++u) {
        sm[u] = 0.f;
        #pragma unroll
        for (int d = 0; d < DK_; ++d) acc[u][d] = 0.f;
    }
    __syncthreads();                 // stage visible
    int mbase = ks * 256 + wid * 32;
    int lbase = wid * 32;
    #pragma unroll 2
    for (int j = 0; j < 32; ++j) {
        float kk[16];
        {
            const float4* kr = (const float4*)(kst + ((lbase + j) << 4));
            *(float4*)&kk[0] = kr[0]; *(float4*)&kk[4] = kr[1];
            *(float4*)&kk[8] = kr[2]; *(float4*)&kk[12] = kr[3];
        }
        int m = mbase + j;
        float wx = cb[m * 3], wy = cb[m * 3 + 1], wz = cb[m * 3 + 2];
        float p[QPL_];
        #pragma unroll
        for (int u = 0; u < QPL_; ++u) {
            float dot = 0.f;
            #pragma unroll
            for (int d = 0; d < DK_; ++d) dot += qv[u][d] * kk[d];
            p[u] = __expf(dot * 0.25f + alpha * (wx * cx[u] + wy * cy[u] + wz * cz[u]));
            sm[u] += p[u];
        }
        float vv[16];
        {
            const float4* vr = (const float4*)(vst + ((lbase + j) << 4));
            *(float4*)&vv[0] = vr[0]; *(float4*)&vv[4] = vr[1];
            *(float4*)&vv[8] = vr[2]; *(float4*)&vv[12] = vr[3];
        }
        #pragma unroll
        for (int u = 0; u < QPL_; ++u)
            #pragma unroll
            for (int d = 0; d < DK_; ++d) acc[u][d] += p[u] * vv[d];
    }
    __syncthreads();                 // done reading stage
    #pragma unroll
    for (int u = 0; u < QPL_; ++u) ssum[wid * 256 + u * 64 + lane] = sm[u];
    int qi = threadIdx.x & 63;
    int dq = threadIdx.x >> 6;       // 0..7, 2 d's each
    #pragma unroll
    for (int r = 0; r < QPL_; ++r) {
        #pragma unroll
        for (int d = 0; d < DK_; ++d) sacc[lane * 129 + wid * DK_ + d] = acc[r][d];
        __syncthreads();
        int n = nb * 256 + r * 64 + qi;
        float* o = pp + (((size_t)bh * N_ + n) * KSP_ + ks) * PREC_;
        if (dq == 0) {
            float gsum = 0.f;
            #pragma unroll
            for (int w = 0; w < AW_; ++w) gsum += ssum[w * 256 + r * 64 + qi];
            o[0] = gsum;
        }
        #pragma unroll
        for (int dd = 0; dd < 2; ++dd) {
            int d = dq * 2 + dd;
            float a = 0.f;
            #pragma unroll
            for (int w = 0; w < AW_; ++w) a += sacc[qi * 129 + w * DK_ + d];
            o[1 + d] = a;
        }
        __syncthreads();
    }
}

// ---------------- column mean over N (global feature) ----------------------
__global__ void colmean_kernel(const float* __restrict__ x,
                               float* __restrict__ gc) {
    int b = blockIdx.x;
    int d = threadIdx.x & 127;
    int sl = threadIdx.x >> 7;
    __shared__ float part[4][128];
    float s = 0.f;
    const float* xb = x + (size_t)b * N_ * D_;
    for (int n = sl * 256; n < sl * 256 + 256; ++n) s += xb[(size_t)n * D_ + d];
    part[sl][d] = s;
    __syncthreads();
    if (sl == 0)
        gc[b * D_ + d] = (part[0][d] + part[1][d] + part[2][d] + part[3][d]) * (1.0f / N_);
}

// ---------------------------------------------------------------------------
extern "C" void kernel_launch(void* const* d_in, const int* in_sizes, int n_in,
                              void* d_out, int out_size, void* d_ws, size_t ws_size,
                              hipStream_t stream) {
    (void)in_sizes; (void)n_in; (void)out_size; (void)ws_size;
    const float* coords = (const float*)d_in[0];
    const float* gcn_w0 = (const float*)d_in[1];
    const float* gcn_b0 = (const float*)d_in[2];
    const float* gcn_w1 = (const float*)d_in[3];
    const float* gcn_b1 = (const float*)d_in[4];
    const float* enc_fw = (const float*)d_in[5];
    const float* enc_fb = (const float*)d_in[6];
    const float* t_wq   = (const float*)d_in[7];
    const float* t_bq   = (const float*)d_in[8];
    const float* t_wk   = (const float*)d_in[9];
    const float* t_bk   = (const float*)d_in[10];
    const float* t_wv   = (const float*)d_in[11];
    const float* t_bv   = (const float*)d_in[12];
    const float* t_alpha= (const float*)d_in[13];
    const float* t_f1w  = (const float*)d_in[14];
    const float* t_f1b  = (const float*)d_in[15];
    const float* t_f2w  = (const float*)d_in[16];
    const float* t_f2b  = (const float*)d_in[17];
    const float* t_ln1g = (const float*)d_in[18];
    const float* t_ln1b = (const float*)d_in[19];
    const float* t_ln2g = (const float*)d_in[20];
    const float* t_ln2b = (const float*)d_in[21];
    const float* dec_w1 = (const float*)d_in[22];
    const float* dec_b1 = (const float*)d_in[23];
    const float* dec_w2 = (const float*)d_in[24];
    const float* dec_b2 = (const float*)d_in[25];
    const float* st_sw1 = (const float*)d_in[26];
    const float* st_sb1 = (const float*)d_in[27];
    const float* st_sw2 = (const float*)d_in[28];
    const float* st_sb2 = (const float*)d_in[29];
    const float* st_dw  = (const float*)d_in[30];
    const float* st_db  = (const float*)d_in[31];
    const float* st_cw  = (const float*)d_in[32];
    const float* st_cb  = (const float*)d_in[33];
    float* out = (float*)d_out;

    // ---- workspace carve ----
    char* ws = (char*)d_ws;
    size_t off = 0;
    auto alloc = [&](size_t bytes) -> void* {
        void* p = ws + off;
        off += (bytes + 255) & ~(size_t)255;
        return p;
    };
    int*   knn   = (int*)  alloc((size_t)B_ * N_ * KG_ * 4);
    float* app   = (float*)alloc((size_t)B_ * H_ * N_ * KSP_ * PREC_ * 4);
    float* x64   = (float*)alloc((size_t)B_ * N_ * 64 * 4);
    float* xb    = (float*)alloc((size_t)B_ * N_ * D_ * 4);
    float* x     = (float*)alloc((size_t)B_ * N_ * D_ * 4);
    float* q     = (float*)alloc((size_t)B_ * N_ * D_ * 4);
    float* k     = (float*)alloc((size_t)B_ * N_ * D_ * 4);
    float* v     = (float*)alloc((size_t)B_ * N_ * D_ * 4);
    float* ffh   = (float*)alloc((size_t)B_ * N_ * 512 * 4);
    float* gc    = (float*)alloc((size_t)B_ * D_ * 4);
    float* pts0  = (float*)alloc((size_t)B_ * COARSE_ * 3 * 4);
    float* pts1  = (float*)alloc((size_t)B_ * 1024 * 3 * 4);
    float* pts2  = (float*)alloc((size_t)B_ * 2048 * 3 * 4);
    float* seedh = (float*)alloc((size_t)B_ * 2048 * 128 * 4);

    const int rows = B_ * N_;   // 2048

    // ---- graph encoder (+ layer-0 QKV) ----
    knn_gcn0_kernel<<<rows / 4, 256, 0, stream>>>(coords, gcn_w0, gcn_b0, knn, x64);
    enc_fused_kernel<<<rows / 8, 256, 0, stream>>>(
        x64, knn, gcn_w1, gcn_b1, enc_fw, enc_fb,
        t_wq, t_bq, t_wk, t_bk, t_wv, t_bv, x, q, k, v);

    // ---- transformer ----
    for (int i = 0; i < L_; ++i) {
        attn_part<<<B_ * H_ * (N_ / 256) * KSP_, 512, 0, stream>>>(q, k, v, coords, t_alpha, i, app);
        gemm_ffn1_kernel<<<dim3(rows / 8, 4), 256, 0, stream>>>(
            app, x, t_ln1g + i * 128, t_ln1b + i * 128,
            t_f1w + i * 128 * 512, t_f1b + i * 512, xb, ffh);
        if (i < L_ - 1) {
            int j = i + 1;
            lnqkv_kernel<false><<<rows / 8, 256, 0, stream>>>(
                ffh, t_f2w + i * 512 * 128, t_f2b + i * 128, xb,
                t_ln2g + i * 128, t_ln2b + i * 128,
                t_wq + j * 16384, t_bq + j * 128, t_wk + j * 16384, t_bk + j * 128,
                t_wv + j * 16384, t_bv + j * 128, x, q, k, v);
        } else {
            lnqkv_kernel<true><<<rows / 8, 256, 0, stream>>>(
                ffh, t_f2w + i * 512 * 128, t_f2b + i * 128, xb,
                t_ln2g + i * 128, t_ln2b + i * 128,
                nullptr, nullptr, nullptr, nullptr, nullptr, nullptr,
                x, nullptr, nullptr, nullptr);
        }
    }

    // ---- decoder coarse ----
    colmean_kernel<<<B_, 512, 0, stream>>>(x, gc);
    dec12_kernel<<<12, 256, 0, stream>>>(gc, dec_w1, dec_b1, dec_w2, dec_b2, pts0);

    // ---- refine stages ----
    const float* pred = pts0;
    float* outs[3] = { pts1, pts2, out };
    int Nq = COARSE_;
    for (int s = 0; s < 3; ++s) {
        int srows = B_ * Nq;
        loc_fused_kernel<<<srows / 4, 256, 0, stream>>>(
            coords, pred, st_sw1 + s * 6 * 128, st_sb1 + s * 128, seedh, Nq);
        refine_tail_kernel<<<srows / 8, 256, 0, stream>>>(
            seedh, st_sw2 + s * 128 * 128, st_sb2 + s * 128,
            st_dw + s * 128 * 256, st_db + s * 128,
            st_cw + s * 3 * 128, st_cb + s * 3, pred, outs[s]);
        pred = outs[s];
        Nq <<= 1;
    }
}

// Round 21
// 377.602 us; speedup vs baseline: 1.0719x; 1.0719x over previous
//
#include <hip/hip_runtime.h>

// ---------------------------------------------------------------------------
// FullModelSnowflake.  R20: revert R19's serializing fusions (lnqkv/enc_fused
// chained independent QKV GEMMs -> 3x span; 768 parallel blocks beat 256
// serial ones).  Back to R18 structure; keep knn+gcn0 fusion (grid-neutral).
// 27 launches.
// ---------------------------------------------------------------------------

#define B_ 2
#define N_ 1024
#define D_ 128
#define H_ 8
#define DK_ 16
#define L_ 4
#define KG_ 16
#define KLOC_ 8
#define COARSE_ 512
#define AW_ 8            // waves per attention block
#define KSP_ 4           // block-level key splits
#define PREC_ 17         // floats per attention partial (sum + 16 acc)
#define QPL_ 4           // queries per lane

static __device__ __forceinline__ float half_sum(float v) {
    #pragma unroll
    for (int off = 16; off > 0; off >>= 1) v += __shfl_xor(v, off);
    return v;
}

// ---------------- LDS-staged GEMM body: returns this thread's acc ----------
template <int CIN, bool RELU, bool BIAS_HALF>
static __device__ __forceinline__ float4 gemm_body(
        const float* __restrict__ X, const float* __restrict__ W,
        const float* __restrict__ bias, int wstride, int col0) {
    __shared__ float Xs[8 * CIN];
    __shared__ float Ws[64][128];
    int tid = threadIdx.x;
    int row0 = blockIdx.x * 8;
    constexpr int NX4 = 2 * CIN;
    {
        const float4* xg = (const float4*)(X + (size_t)row0 * CIN);
        float4* xs4 = (float4*)Xs;
        #pragma unroll
        for (int i = 0; i < (NX4 + 255) / 256; ++i) {
            int t = tid + i * 256;
            if ((NX4 % 256 == 0) || t < NX4) xs4[t] = xg[t];
        }
    }
    int col4 = (tid & 31) << 2;
    int rowl = tid >> 5;
    float4 acc;
    if (BIAS_HALF) {
        acc.x = bias[(col0 + col4) >> 1];
        acc.y = bias[(col0 + col4 + 1) >> 1];
        acc.z = bias[(col0 + col4 + 2) >> 1];
        acc.w = bias[(col0 + col4 + 3) >> 1];
    } else {
        acc = *(const float4*)(bias + col0 + col4);
    }
    for (int c0 = 0; c0 < CIN; c0 += 64) {
        __syncthreads();
        #pragma unroll
        for (int i = 0; i < 8; ++i) {
            int flat = tid + i * 256;
            int wr = flat >> 5, wc = (flat & 31) << 2;
            *(float4*)&Ws[wr][wc] =
                *(const float4*)(W + (size_t)(c0 + wr) * wstride + col0 + wc);
        }
        __syncthreads();
        const float* xrow = Xs + rowl * CIN + c0;
        #pragma unroll
        for (int c = 0; c < 64; ++c) {
            float xv = xrow[c];
            float4 w = *(const float4*)&Ws[c][col4];
            acc.x += xv * w.x; acc.y += xv * w.y;
            acc.z += xv * w.z; acc.w += xv * w.w;
        }
    }
    if (RELU) {
        acc.x = fmaxf(acc.x, 0.f); acc.y = fmaxf(acc.y, 0.f);
        acc.z = fmaxf(acc.z, 0.f); acc.w = fmaxf(acc.w, 0.f);
    }
    return acc;
}

template <int CIN, bool RELU, bool BIAS_HALF>
__global__ __launch_bounds__(256) void gemm128_kernel(
        const float* __restrict__ X, const float* __restrict__ W,
        const float* __restrict__ bias, float* __restrict__ Y,
        int wstride, int ystride) {
    int col0 = blockIdx.y * 128;
    float4 acc = gemm_body<CIN, RELU, BIAS_HALF>(X, W, bias, wstride, col0);
    int col4 = (threadIdx.x & 31) << 2;
    int row = blockIdx.x * 8 + (threadIdx.x >> 5);
    *(float4*)(Y + (size_t)row * ystride + col0 + col4) = acc;
}

// GCN layer-2 GEMM: X-stage does the knn gather-average (agg fused).
__global__ __launch_bounds__(256) void gemm_gcn_kernel(
        const float* __restrict__ x64, const int* __restrict__ knn,
        const float* __restrict__ W, const float* __restrict__ bias,
        float* __restrict__ Y) {
    __shared__ float Xs[8 * 64];
    __shared__ float Ws[64][128];
    int tid = threadIdx.x;
    int row0 = blockIdx.x * 8;
    #pragma unroll
    for (int i = 0; i < 2; ++i) {
        int idx = tid + i * 256;
        int r = idx >> 6, c = idx & 63;
        int row = row0 + r;
        int b = row >> 10;
        const int* id = knn + (size_t)row * KG_;
        float val = x64[(size_t)row * 64 + c];
        #pragma unroll
        for (int j = 0; j < KG_; ++j)
            val += x64[((size_t)(b << 10) + id[j]) * 64 + c];
        Xs[idx] = val * (1.0f / (KG_ + 1));
    }
    int col4 = (tid & 31) << 2;
    int rowl = tid >> 5;
    float4 acc = *(const float4*)(bias + col4);
    __syncthreads();
    #pragma unroll
    for (int i = 0; i < 8; ++i) {
        int flat = tid + i * 256;
        int wr = flat >> 5, wc = (flat & 31) << 2;
        *(float4*)&Ws[wr][wc] = *(const float4*)(W + (size_t)wr * 128 + wc);
    }
    __syncthreads();
    const float* xrow = Xs + rowl * 64;
    #pragma unroll
    for (int c = 0; c < 64; ++c) {
        float xv = xrow[c];
        float4 w = *(const float4*)&Ws[c][col4];
        acc.x += xv * w.x; acc.y += xv * w.y;
        acc.z += xv * w.z; acc.w += xv * w.w;
    }
    acc.x = fmaxf(acc.x, 0.f); acc.y = fmaxf(acc.y, 0.f);
    acc.z = fmaxf(acc.z, 0.f); acc.w = fmaxf(acc.w, 0.f);
    int row = row0 + rowl;
    *(float4*)(Y + (size_t)row * 128 + col4) = acc;
}

// GEMM (Cout=128) fused with residual-add + LayerNorm epilogue.
template <int CIN>
__global__ __launch_bounds__(256) void gemm_ln_kernel(
        const float* __restrict__ X, const float* __restrict__ W,
        const float* __restrict__ bias, const float* __restrict__ res,
        const float* __restrict__ g, const float* __restrict__ bt,
        float* __restrict__ Y) {
    float4 acc = gemm_body<CIN, false, false>(X, W, bias, 128, 0);
    int col4 = (threadIdx.x & 31) << 2;
    int row = blockIdx.x * 8 + (threadIdx.x >> 5);
    float4 r = *(const float4*)(res + (size_t)row * D_ + col4);
    acc.x += r.x; acc.y += r.y; acc.z += r.z; acc.w += r.w;
    float mean = half_sum(acc.x + acc.y + acc.z + acc.w) * (1.0f / D_);
    float dx = acc.x - mean, dy = acc.y - mean, dz = acc.z - mean, dw = acc.w - mean;
    float var = half_sum(dx * dx + dy * dy + dz * dz + dw * dw) * (1.0f / D_);
    float rstd = rsqrtf(var + 1e-5f);
    float4 gv = *(const float4*)(g + col4);
    float4 bv = *(const float4*)(bt + col4);
    float4 o;
    o.x = dx * rstd * gv.x + bv.x;
    o.y = dy * rstd * gv.y + bv.y;
    o.z = dz * rstd * gv.z + bv.z;
    o.w = dw * rstd * gv.w + bv.w;
    *(float4*)(Y + (size_t)row * D_ + col4) = o;
}

// FFN1 GEMM with fused attn-final-merge + residual + LN in the X-stage.
__global__ __launch_bounds__(256) void gemm_ffn1_kernel(
        const float* __restrict__ pp, const float* __restrict__ xin,
        const float* __restrict__ g, const float* __restrict__ bt,
        const float* __restrict__ W, const float* __restrict__ bias,
        float* __restrict__ xln, float* __restrict__ Y) {
    __shared__ float Xs[8 * 128];
    __shared__ float Ws[64][128];
    int tid = threadIdx.x;
    int row0 = blockIdx.x * 8;
    int col0 = blockIdx.y * 128;
    int col4 = (tid & 31) << 2;
    int rowl = tid >> 5;
    {
        int row = row0 + rowl;
        int b = row >> 10, n = row & (N_ - 1);
        int h = col4 >> 4, d0 = col4 & 15;
        const float* p = pp + (((size_t)(b * 8 + h) * N_ + n) * KSP_) * PREC_;
        float gsum = 0.f, a0 = 0.f, a1 = 0.f, a2 = 0.f, a3 = 0.f;
        #pragma unroll
        for (int s = 0; s < KSP_; ++s) {
            const float* ps = p + s * PREC_;
            gsum += ps[0];
            a0 += ps[1 + d0]; a1 += ps[2 + d0]; a2 += ps[3 + d0]; a3 += ps[4 + d0];
        }
        float inv = 1.0f / gsum;
        float4 xv = *(const float4*)(xin + (size_t)row * D_ + col4);
        float v0 = a0 * inv + xv.x;
        float v1 = a1 * inv + xv.y;
        float v2 = a2 * inv + xv.z;
        float v3 = a3 * inv + xv.w;
        float mean = half_sum(v0 + v1 + v2 + v3) * (1.0f / D_);
        float dx = v0 - mean, dy = v1 - mean, dz = v2 - mean, dw = v3 - mean;
        float var = half_sum(dx * dx + dy * dy + dz * dz + dw * dw) * (1.0f / D_);
        float rstd = rsqrtf(var + 1e-5f);
        float4 gv = *(const float4*)(g + col4);
        float4 bv = *(const float4*)(bt + col4);
        float4 o;
        o.x = dx * rstd * gv.x + bv.x;
        o.y = dy * rstd * gv.y + bv.y;
        o.z = dz * rstd * gv.z + bv.z;
        o.w = dw * rstd * gv.w + bv.w;
        *(float4*)&Xs[rowl * 128 + col4] = o;
        if (blockIdx.y == 0)
            *(float4*)(xln + (size_t)row * D_ + col4) = o;
    }
    float4 acc = *(const float4*)(bias + col0 + col4);
    for (int c0 = 0; c0 < 128; c0 += 64) {
        __syncthreads();
        #pragma unroll
        for (int i = 0; i < 8; ++i) {
            int flat = tid + i * 256;
            int wr = flat >> 5, wc = (flat & 31) << 2;
            *(float4*)&Ws[wr][wc] =
                *(const float4*)(W + (size_t)(c0 + wr) * 512 + col0 + wc);
        }
        __syncthreads();
        const float* xrow = Xs + rowl * 128 + c0;
        #pragma unroll
        for (int c = 0; c < 64; ++c) {
            float xv = xrow[c];
            float4 w = *(const float4*)&Ws[c][col4];
            acc.x += xv * w.x; acc.y += xv * w.y;
            acc.z += xv * w.z; acc.w += xv * w.w;
        }
    }
    acc.x = fmaxf(acc.x, 0.f); acc.y = fmaxf(acc.y, 0.f);
    acc.z = fmaxf(acc.z, 0.f); acc.w = fmaxf(acc.w, 0.f);
    int row = row0 + rowl;
    *(float4*)(Y + (size_t)row * 512 + col0 + col4) = acc;
}

// fused QKV: 3 W-panels via blockIdx.y; outputs stored HEAD-MAJOR [bh][n][16]
__global__ __launch_bounds__(256) void qkv3_kernel(
        const float* __restrict__ X,
        const float* __restrict__ Wq, const float* __restrict__ bq,
        const float* __restrict__ Wk, const float* __restrict__ bk,
        const float* __restrict__ Wv, const float* __restrict__ bv,
        float* __restrict__ Q, float* __restrict__ K, float* __restrict__ V) {
    const float* W; const float* bias; float* Y;
    if (blockIdx.y == 0)      { W = Wq; bias = bq; Y = Q; }
    else if (blockIdx.y == 1) { W = Wk; bias = bk; Y = K; }
    else                      { W = Wv; bias = bv; Y = V; }
    float4 acc = gemm_body<128, false, false>(X, W, bias, 128, 0);
    int col4 = (threadIdx.x & 31) << 2;
    int row = blockIdx.x * 8 + (threadIdx.x >> 5);
    int b = row >> 10, n = row & (N_ - 1);
    int h = col4 >> 4, d = col4 & 15;
    *(float4*)(Y + (((size_t)(b * 8 + h) * N_ + n) << 4) + d) = acc;
}

// ---------------- KNN (k=16) + GCN layer-1 fused ---------------------------
__global__ __launch_bounds__(256) void knn_gcn0_kernel(
        const float* __restrict__ coords,
        const float* __restrict__ w0, const float* __restrict__ b0,
        int* __restrict__ knn, float* __restrict__ x64) {
    __shared__ float4 sc[N_];
    int wid = threadIdx.x >> 6;
    int lane = threadIdx.x & 63;
    size_t q = (size_t)blockIdx.x * 4 + wid;
    int b = (int)(q >> 10), n = (int)(q & (N_ - 1));
    const float* cb = coords + (size_t)b * N_ * 3;
    for (int i = threadIdx.x; i < N_; i += 256) {
        float x = cb[i * 3], y = cb[i * 3 + 1], z = cb[i * 3 + 2];
        sc[i] = make_float4(x, y, z, x * x + y * y + z * z);
    }
    __syncthreads();
    float4 qc = sc[n];
    float qx = qc.x, qy = qc.y, qz = qc.z, q2 = qc.w;
    float ld[16];
    #pragma unroll
    for (int j = 0; j < 16; ++j) {
        int m = (j << 6) | lane;
        float4 c = sc[m];
        float dot = qx * c.x + qy * c.y + qz * c.z;
        float d = (q2 - 2.0f * dot) + c.w;
        ld[j] = (m == n) ? 3e38f : d;
    }
    int* o = knn + q * KG_;
    float ax = qx, ay = qy, az = qz;     // self + neighbors
    #pragma unroll
    for (int r = 0; r < KG_; ++r) {
        float dm = ld[0]; int im = lane;
        #pragma unroll
        for (int j = 1; j < 16; ++j) {
            int mj = (j << 6) | lane;
            bool lt = (ld[j] < dm) || (ld[j] == dm && mj < im);
            dm = lt ? ld[j] : dm; im = lt ? mj : im;
        }
        #pragma unroll
        for (int off = 32; off > 0; off >>= 1) {
            float d2 = __shfl_xor(dm, off); int i2 = __shfl_xor(im, off);
            bool lt = (d2 < dm) || (d2 == dm && i2 < im);
            dm = lt ? d2 : dm; im = lt ? i2 : im;
        }
        if (lane == 0) o[r] = im;
        float4 w = sc[im];               // broadcast
        ax += w.x; ay += w.y; az += w.z;
        if ((im & 63) == lane) {
            #pragma unroll
            for (int j = 0; j < 16; ++j) if ((im >> 6) == j) ld[j] = 3e38f;
        }
    }
    float s = 1.0f / (KG_ + 1);
    ax *= s; ay *= s; az *= s;
    float acc = b0[lane] + ax * w0[lane] + ay * w0[64 + lane] + az * w0[128 + lane];
    x64[q * 64 + lane] = fmaxf(acc, 0.f);
}

// ---------------- single-kernel local-KNN + mean + seed linear -------------
__global__ __launch_bounds__(256) void loc_fused_kernel(
        const float* __restrict__ part, const float* __restrict__ pred,
        const float* __restrict__ sw1, const float* __restrict__ sb1,
        float* __restrict__ seedh, int Nq) {
    __shared__ float4 sc[N_];
    int wid = threadIdx.x >> 6;
    int lane = threadIdx.x & 63;
    size_t q = (size_t)blockIdx.x * 4 + wid;
    int b = (int)(q / Nq);
    const float* pb = part + (size_t)b * N_ * 3;
    for (int i = threadIdx.x; i < N_; i += 256) {
        float x = pb[i * 3], y = pb[i * 3 + 1], z = pb[i * 3 + 2];
        sc[i] = make_float4(x, y, z, x * x + y * y + z * z);
    }
    __syncthreads();
    const float* pr = pred + q * 3;
    float qx = pr[0], qy = pr[1], qz = pr[2];
    float q2 = qx * qx + qy * qy + qz * qz;
    float ld[16];
    #pragma unroll
    for (int j = 0; j < 16; ++j) {
        int m = (j << 6) | lane;
        float4 c = sc[m];
        float dot = qx * c.x + qy * c.y + qz * c.z;
        ld[j] = (q2 - 2.0f * dot) + c.w;
    }
    float sx = 0.f, sy = 0.f, sz = 0.f;
    #pragma unroll
    for (int r = 0; r < KLOC_; ++r) {
        float dm = ld[0]; int im = lane;
        #pragma unroll
        for (int j = 1; j < 16; ++j) {
            int mj = (j << 6) | lane;
            bool lt = (ld[j] < dm) || (ld[j] == dm && mj < im);
            dm = lt ? ld[j] : dm; im = lt ? mj : im;
        }
        #pragma unroll
        for (int off = 32; off > 0; off >>= 1) {
            float d2 = __shfl_xor(dm, off); int i2 = __shfl_xor(im, off);
            bool lt = (d2 < dm) || (d2 == dm && i2 < im);
            dm = lt ? d2 : dm; im = lt ? i2 : im;
        }
        float4 w = sc[im];               // broadcast
        sx += w.x; sy += w.y; sz += w.z;
        if ((im & 63) == lane) {
            #pragma unroll
            for (int j = 0; j < 16; ++j) if ((im >> 6) == j) ld[j] = 3e38f;
        }
    }
    float comb[6];
    comb[0] = qx; comb[1] = qy; comb[2] = qz;
    comb[3] = sx * (1.0f / KLOC_);
    comb[4] = sy * (1.0f / KLOC_);
    comb[5] = sz * (1.0f / KLOC_);
    float* so = seedh + q * 128;
    #pragma unroll
    for (int half = 0; half < 2; ++half) {
        int c = lane + half * 64;
        float acc = sb1[c];
        #pragma unroll
        for (int i = 0; i < 6; ++i) acc += comb[i] * sw1[i * 128 + c];
        so[c] = fmaxf(acc, 0.f);
    }
}

// ---------------- refine tail: seed GEMM + convt + child in one kernel -----
__global__ __launch_bounds__(256) void refine_tail_kernel(
        const float* __restrict__ seedh,
        const float* __restrict__ sw2, const float* __restrict__ sb2,
        const float* __restrict__ dw, const float* __restrict__ db,
        const float* __restrict__ cw, const float* __restrict__ cb,
        const float* __restrict__ pred, float* __restrict__ outp) {
    __shared__ float Xs[8 * 128];
    __shared__ float Ws[64][128];
    __shared__ float Sd[8 * 128];
    __shared__ float Hb[8 * 256];
    int tid = threadIdx.x;
    int row0 = blockIdx.x * 8;
    int col4 = (tid & 31) << 2;
    int rowl = tid >> 5;
    {
        const float4* xg = (const float4*)(seedh + (size_t)row0 * 128);
        float4* xs4 = (float4*)Xs;
        xs4[tid] = xg[tid];
    }
    float4 acc = *(const float4*)(sb2 + col4);
    for (int c0 = 0; c0 < 128; c0 += 64) {
        __syncthreads();
        #pragma unroll
        for (int i = 0; i < 8; ++i) {
            int flat = tid + i * 256;
            int wr = flat >> 5, wc = (flat & 31) << 2;
            *(float4*)&Ws[wr][wc] =
                *(const float4*)(sw2 + (size_t)(c0 + wr) * 128 + wc);
        }
        __syncthreads();
        const float* xrow = Xs + rowl * 128 + c0;
        #pragma unroll
        for (int c = 0; c < 64; ++c) {
            float xv = xrow[c];
            float4 w = *(const float4*)&Ws[c][col4];
            acc.x += xv * w.x; acc.y += xv * w.y;
            acc.z += xv * w.z; acc.w += xv * w.w;
        }
    }
    __syncthreads();
    *(float4*)&Sd[rowl * 128 + col4] = acc;
    #pragma unroll
    for (int panel = 0; panel < 2; ++panel) {
        int col0 = panel * 128;
        float4 a2;
        a2.x = db[(col0 + col4) >> 1];
        a2.y = db[(col0 + col4 + 1) >> 1];
        a2.z = db[(col0 + col4 + 2) >> 1];
        a2.w = db[(col0 + col4 + 3) >> 1];
        for (int c0 = 0; c0 < 128; c0 += 64) {
            __syncthreads();
            #pragma unroll
            for (int i = 0; i < 8; ++i) {
                int flat = tid + i * 256;
                int wr = flat >> 5, wc = (flat & 31) << 2;
                *(float4*)&Ws[wr][wc] =
                    *(const float4*)(dw + (size_t)(c0 + wr) * 256 + col0 + wc);
            }
            __syncthreads();
            const float* xrow = Sd + rowl * 128 + c0;
            #pragma unroll
            for (int c = 0; c < 64; ++c) {
                float xv = xrow[c];
                float4 w = *(const float4*)&Ws[c][col4];
                a2.x += xv * w.x; a2.y += xv * w.y;
                a2.z += xv * w.z; a2.w += xv * w.w;
            }
        }
        a2.x = fmaxf(a2.x, 0.f); a2.y = fmaxf(a2.y, 0.f);
        a2.z = fmaxf(a2.z, 0.f); a2.w = fmaxf(a2.w, 0.f);
        __syncthreads();
        *(float4*)&Hb[rowl * 256 + col0 + col4] = a2;
    }
    __syncthreads();
    if (tid < 48) {
        int r = tid / 6, rem = tid % 6;
        int t = rem / 3, p = rem % 3;
        const float* hr = Hb + r * 256;
        float a = cb[p];
        #pragma unroll 4
        for (int o = 0; o < 128; ++o) a += hr[o * 2 + t] * cw[p * 128 + o];
        size_t row = row0 + r;
        outp[row * 6 + t * 3 + p] = pred[row * 3 + p] + a;
    }
}

// ---------------- decoder: dec_w1 + dec_w2 fused ---------------------------
__global__ __launch_bounds__(256) void dec12_kernel(
        const float* __restrict__ gc,
        const float* __restrict__ w1, const float* __restrict__ b1,
        const float* __restrict__ w2, const float* __restrict__ b2,
        float* __restrict__ pts0) {
    __shared__ float gcs[128];
    __shared__ float dech[128];
    int tid = threadIdx.x;
    int row = blockIdx.x / 6;
    int colb = (blockIdx.x % 6) * 256;
    if (tid < 128) gcs[tid] = gc[row * 128 + tid];
    __syncthreads();
    if (tid < 128) {
        float a = b1[tid];
        #pragma unroll 4
        for (int c = 0; c < 128; ++c) a += gcs[c] * w1[c * 128 + tid];
        dech[tid] = fmaxf(a, 0.f);
    }
    __syncthreads();
    int col = colb + tid;
    float a = b2[col];
    #pragma unroll 4
    for (int c = 0; c < 128; ++c) a += dech[c] * w2[(size_t)c * 1536 + col];
    pts0[(size_t)row * 1536 + col] = a;
}

// ---------------- attention: 4 queries/lane, LDS-staged K/V ----------------
__global__ __launch_bounds__(512) void attn_part(
        const float* __restrict__ q,
        const float* __restrict__ k,
        const float* __restrict__ v,
        const float* __restrict__ coords,
        const float* __restrict__ alphap, int layer,
        float* __restrict__ pp) {
    __shared__ float smem[10304];    // stage 8192 | merge: ssum 2048 + sacc 8256
    float* kst = smem;               // [256][16]
    float* vst = smem + 4096;        // [256][16]
    float* ssum = smem;              // [8][256]   (merge phase)
    float* sacc = smem + 2048;       // [64][129]
    int bh = blockIdx.x & 15;        // b*8 + h
    int t = blockIdx.x >> 4;         // nb*KSP + ks
    int ks = t & (KSP_ - 1);
    int nb = t >> 2;                 // [0, 4)
    int b = bh >> 3;
    int wid = threadIdx.x >> 6;
    int lane = threadIdx.x & 63;
    float alpha = alphap[layer];
    {
        const float4* kg = (const float4*)(k + (((size_t)bh * N_ + ks * 256) << 4));
        const float4* vg = (const float4*)(v + (((size_t)bh * N_ + ks * 256) << 4));
        float4* ks4 = (float4*)kst;
        float4* vs4 = (float4*)vst;
        #pragma unroll
        for (int i = 0; i < 2; ++i) {
            int idx = threadIdx.x + i * 512;
            ks4[idx] = kg[idx];
            vs4[idx] = vg[idx];
        }
    }
    int n0 = nb * 256 + lane;        // queries n0 + u*64, u=0..3
    const float* cb = coords + (size_t)b * N_ * 3;
    float qv[QPL_][DK_];
    float cx[QPL_], cy[QPL_], cz[QPL_];
    #pragma unroll
    for (int u = 0; u < QPL_; ++u) {
        const float* qp = q + (((size_t)bh * N_ + n0 + u * 64) << 4);
        #pragma unroll
        for (int d = 0; d < DK_; ++d) qv[u][d] = qp[d];
        int nn = n0 + u * 64;
        cx[u] = cb[nn * 3]; cy[u] = cb[nn * 3 + 1]; cz[u] = cb[nn * 3 + 2];
    }
    float sm[QPL_];
    float acc[QPL_][DK_];
    #pragma unroll
    for (int u = 0; u < QPL_; ++u) {
        sm[u] = 0.f;
        #pragma unroll
        for (int d = 0; d < DK_; ++d) acc[u][d] = 0.f;
    }
    __syncthreads();                 // stage visible
    int mbase = ks * 256 + wid * 32;
    int lbase = wid * 32;
    #pragma unroll 2
    for (int j = 0; j < 32; ++j) {
        float kk[16];
        {
            const float4* kr = (const float4*)(kst + ((lbase + j) << 4));
            *(float4*)&kk[0] = kr[0]; *(float4*)&kk[4] = kr[1];
            *(float4*)&kk[8] = kr[2]; *(float4*)&kk[12] = kr[3];
        }
        int m = mbase + j;
        float wx = cb[m * 3], wy = cb[m * 3 + 1], wz = cb[m * 3 + 2];
        float p[QPL_];
        #pragma unroll
        for (int u = 0; u < QPL_; ++u) {
            float dot = 0.f;
            #pragma unroll
            for (int d = 0; d < DK_; ++d) dot += qv[u][d] * kk[d];
            p[u] = __expf(dot * 0.25f + alpha * (wx * cx[u] + wy * cy[u] + wz * cz[u]));
            sm[u] += p[u];
        }
        float vv[16];
        {
            const float4* vr = (const float4*)(vst + ((lbase + j) << 4));
            *(float4*)&vv[0] = vr[0]; *(float4*)&vv[4] = vr[1];
            *(float4*)&vv[8] = vr[2]; *(float4*)&vv[12] = vr[3];
        }
        #pragma unroll
        for (int u = 0; u < QPL_; ++u)
            #pragma unroll
            for (int d = 0; d < DK_; ++d) acc[u][d] += p[u] * vv[d];
    }
    __syncthreads();                 // done reading stage
    #pragma unroll
    for (int u = 0; u < QPL_; ++u) ssum[wid * 256 + u * 64 + lane] = sm[u];
    int qi = threadIdx.x & 63;
    int dq = threadIdx.x >> 6;       // 0..7, 2 d's each
    #pragma unroll
    for (int r = 0; r < QPL_; ++r) {
        #pragma unroll
        for (int d = 0; d < DK_; ++d) sacc[lane * 129 + wid * DK_ + d] = acc[r][d];
        __syncthreads();
        int n = nb * 256 + r * 64 + qi;
        float* o = pp + (((size_t)bh * N_ + n) * KSP_ + ks) * PREC_;
        if (dq == 0) {
            float gsum = 0.f;
            #pragma unroll
            for (int w = 0; w < AW_; ++w) gsum += ssum[w * 256 + r * 64 + qi];
            o[0] = gsum;
        }
        #pragma unroll
        for (int dd = 0; dd < 2; ++dd) {
            int d = dq * 2 + dd;
            float a = 0.f;
            #pragma unroll
            for (int w = 0; w < AW_; ++w) a += sacc[qi * 129 + w * DK_ + d];
            o[1 + d] = a;
        }
        __syncthreads();
    }
}

// ---------------- column mean over N (global feature) ----------------------
__global__ void colmean_kernel(const float* __restrict__ x,
                               float* __restrict__ gc) {
    int b = blockIdx.x;
    int d = threadIdx.x & 127;
    int sl = threadIdx.x >> 7;
    __shared__ float part[4][128];
    float s = 0.f;
    const float* xb = x + (size_t)b * N_ * D_;
    for (int n = sl * 256; n < sl * 256 + 256; ++n) s += xb[(size_t)n * D_ + d];
    part[sl][d] = s;
    __syncthreads();
    if (sl == 0)
        gc[b * D_ + d] = (part[0][d] + part[1][d] + part[2][d] + part[3][d]) * (1.0f / N_);
}

// ---------------------------------------------------------------------------
extern "C" void kernel_launch(void* const* d_in, const int* in_sizes, int n_in,
                              void* d_out, int out_size, void* d_ws, size_t ws_size,
                              hipStream_t stream) {
    (void)in_sizes; (void)n_in; (void)out_size; (void)ws_size;
    const float* coords = (const float*)d_in[0];
    const float* gcn_w0 = (const float*)d_in[1];
    const float* gcn_b0 = (const float*)d_in[2];
    const float* gcn_w1 = (const float*)d_in[3];
    const float* gcn_b1 = (const float*)d_in[4];
    const float* enc_fw = (const float*)d_in[5];
    const float* enc_fb = (const float*)d_in[6];
    const float* t_wq   = (const float*)d_in[7];
    const float* t_bq   = (const float*)d_in[8];
    const float* t_wk   = (const float*)d_in[9];
    const float* t_bk   = (const float*)d_in[10];
    const float* t_wv   = (const float*)d_in[11];
    const float* t_bv   = (const float*)d_in[12];
    const float* t_alpha= (const float*)d_in[13];
    const float* t_f1w  = (const float*)d_in[14];
    const float* t_f1b  = (const float*)d_in[15];
    const float* t_f2w  = (const float*)d_in[16];
    const float* t_f2b  = (const float*)d_in[17];
    const float* t_ln1g = (const float*)d_in[18];
    const float* t_ln1b = (const float*)d_in[19];
    const float* t_ln2g = (const float*)d_in[20];
    const float* t_ln2b = (const float*)d_in[21];
    const float* dec_w1 = (const float*)d_in[22];
    const float* dec_b1 = (const float*)d_in[23];
    const float* dec_w2 = (const float*)d_in[24];
    const float* dec_b2 = (const float*)d_in[25];
    const float* st_sw1 = (const float*)d_in[26];
    const float* st_sb1 = (const float*)d_in[27];
    const float* st_sw2 = (const float*)d_in[28];
    const float* st_sb2 = (const float*)d_in[29];
    const float* st_dw  = (const float*)d_in[30];
    const float* st_db  = (const float*)d_in[31];
    const float* st_cw  = (const float*)d_in[32];
    const float* st_cb  = (const float*)d_in[33];
    float* out = (float*)d_out;

    // ---- workspace carve ----
    char* ws = (char*)d_ws;
    size_t off = 0;
    auto alloc = [&](size_t bytes) -> void* {
        void* p = ws + off;
        off += (bytes + 255) & ~(size_t)255;
        return p;
    };
    int*   knn   = (int*)  alloc((size_t)B_ * N_ * KG_ * 4);
    float* app   = (float*)alloc((size_t)B_ * H_ * N_ * KSP_ * PREC_ * 4);
    float* x64   = (float*)alloc((size_t)B_ * N_ * 64 * 4);
    float* xb    = (float*)alloc((size_t)B_ * N_ * D_ * 4);
    float* x     = (float*)alloc((size_t)B_ * N_ * D_ * 4);
    float* q     = (float*)alloc((size_t)B_ * N_ * D_ * 4);
    float* k     = (float*)alloc((size_t)B_ * N_ * D_ * 4);
    float* v     = (float*)alloc((size_t)B_ * N_ * D_ * 4);
    float* ffh   = (float*)alloc((size_t)B_ * N_ * 512 * 4);
    float* gc    = (float*)alloc((size_t)B_ * D_ * 4);
    float* pts0  = (float*)alloc((size_t)B_ * COARSE_ * 3 * 4);
    float* pts1  = (float*)alloc((size_t)B_ * 1024 * 3 * 4);
    float* pts2  = (float*)alloc((size_t)B_ * 2048 * 3 * 4);
    float* seedh = (float*)alloc((size_t)B_ * 2048 * 128 * 4);

    const int rows = B_ * N_;   // 2048

    // ---- graph encoder ----
    knn_gcn0_kernel<<<rows / 4, 256, 0, stream>>>(coords, gcn_w0, gcn_b0, knn, x64);
    gemm_gcn_kernel<<<rows / 8, 256, 0, stream>>>(x64, knn, gcn_w1, gcn_b1, xb);
    gemm128_kernel<128, false, false><<<dim3(rows / 8, 1), 256, 0, stream>>>(xb, enc_fw, enc_fb, x, 128, 128);

    // ---- transformer ----
    for (int i = 0; i < L_; ++i) {
        qkv3_kernel<<<dim3(rows / 8, 3), 256, 0, stream>>>(
            x, t_wq + i * 16384, t_bq + i * 128, t_wk + i * 16384, t_bk + i * 128,
            t_wv + i * 16384, t_bv + i * 128, q, k, v);
        attn_part<<<B_ * H_ * (N_ / 256) * KSP_, 512, 0, stream>>>(q, k, v, coords, t_alpha, i, app);
        gemm_ffn1_kernel<<<dim3(rows / 8, 4), 256, 0, stream>>>(
            app, x, t_ln1g + i * 128, t_ln1b + i * 128,
            t_f1w + i * 128 * 512, t_f1b + i * 512, xb, ffh);
        gemm_ln_kernel<512><<<rows / 8, 256, 0, stream>>>(ffh, t_f2w + i * 512 * 128, t_f2b + i * 128, xb, t_ln2g + i * 128, t_ln2b + i * 128, x);
    }

    // ---- decoder coarse ----
    colmean_kernel<<<B_, 512, 0, stream>>>(x, gc);
    dec12_kernel<<<12, 256, 0, stream>>>(gc, dec_w1, dec_b1, dec_w2, dec_b2, pts0);

    // ---- refine stages ----
    const float* pred = pts0;
    float* outs[3] = { pts1, pts2, out };
    int Nq = COARSE_;
    for (int s = 0; s < 3; ++s) {
        int srows = B_ * Nq;
        loc_fused_kernel<<<srows / 4, 256, 0, stream>>>(
            coords, pred, st_sw1 + s * 6 * 128, st_sb1 + s * 128, seedh, Nq);
        refine_tail_kernel<<<srows / 8, 256, 0, stream>>>(
            seedh, st_sw2 + s * 128 * 128, st_sb2 + s * 128,
            st_dw + s * 128 * 256, st_db + s * 128,
            st_cw + s * 3 * 128, st_cb + s * 3, pred, outs[s]);
        pred = outs[s];
        Nq <<= 1;
    }
}